// Round 2
// 151.408 us; speedup vs baseline: 1.0158x; 1.0158x over previous
//
#include <hip/hip_runtime.h>
#include <hip/hip_bf16.h>
#include <stdint.h>

// Problem constants (fixed by setup_inputs)
#define PRIME 2147483647u
#define GAMMA 0.3f
#define K_HASH 128
#define S_SET 8
#define NB 4
#define LQ 1024
#define LK 1024
#define EDIM 512

typedef unsigned short ushort_t;
typedef __attribute__((ext_vector_type(8))) short short8;
typedef __attribute__((ext_vector_type(4))) float f32x4;

static __device__ __forceinline__ unsigned short f2bf(float f) {
    unsigned u = __builtin_bit_cast(unsigned, f);
    u += 0x7FFFu + ((u >> 16) & 1u);   // RNE (no NaN in this problem)
    return (unsigned short)(u >> 16);
}

// async global->LDS, 16B per lane; LDS dst must be lane-contiguous.
static __device__ __forceinline__ void glds16(const void* g, void* l) {
    __builtin_amdgcn_global_load_lds(
        (const __attribute__((address_space(1))) unsigned int*)g,
        (__attribute__((address_space(3))) unsigned int*)l, 16, 0, 0);
}

#define SWZ(r) ((((r) >> 2) & 3) ^ ((r) & 3))

// ---------------------------------------------------------------------------
// 64x64-tile bf16 BT-GEMM device fn: C=A@B^T (+epilogue), f32 accum,
// 4 waves x 32x32, glds width-16, XOR-swizzled LDS, double-buffered.
// ---------------------------------------------------------------------------
#define EPI_ROWBIAS  0
#define EPI_ROWDIV   1
#define EPI_COLBIAS  2

template<int OUTF32, int MODE>
static __device__ void gemm64_dev(
        const ushort_t* __restrict__ A, const ushort_t* __restrict__ B,
        void* __restrict__ C,
        const float* __restrict__ bias, const float* __restrict__ scale,
        int lda, int ldb, int ldc, int Kd, int m0, int n0,
        ushort_t* AsBase, ushort_t* BsBase, int tid) {
    ushort_t (*As)[64 * 32] = (ushort_t (*)[64 * 32])AsBase;
    ushort_t (*Bs)[64 * 32] = (ushort_t (*)[64 * 32])BsBase;
    int w = tid >> 6, lane = tid & 63;
    int wm = (w & 1) * 32, wn = (w >> 1) * 32;
    int mrow = lane & 15, kg = lane >> 4;

    int r = tid >> 2, c = (tid & 3) ^ SWZ(r);
    const ushort_t* pa = A + (size_t)(m0 + r) * lda + c * 8;
    const ushort_t* pb = B + (size_t)(n0 + r) * ldb + c * 8;

    int aoff[2], boff[2];
    #pragma unroll
    for (int s = 0; s < 2; s++) {
        int Ra = wm + s * 16 + mrow;
        aoff[s] = Ra * 32 + (kg ^ SWZ(Ra)) * 8;
        int Rb = wn + s * 16 + mrow;
        boff[s] = Rb * 32 + (kg ^ SWZ(Rb)) * 8;
    }

    f32x4 acc[2][2] = {};
    int nK = Kd >> 5;
    glds16(pa, &As[0][tid * 8]);
    glds16(pb, &Bs[0][tid * 8]);
    for (int i = 0; i < nK; i++) {
        __syncthreads();
        int cur = i & 1, nxt = cur ^ 1;
        if (i + 1 < nK) {
            int k0 = (i + 1) << 5;
            glds16(pa + k0, &As[nxt][tid * 8]);
            glds16(pb + k0, &Bs[nxt][tid * 8]);
        }
        short8 af[2], bh[2];
        #pragma unroll
        for (int s = 0; s < 2; s++) {
            af[s] = *(const short8*)&As[cur][aoff[s]];
            bh[s] = *(const short8*)&Bs[cur][boff[s]];
        }
        #pragma unroll
        for (int ii = 0; ii < 2; ii++)
            #pragma unroll
            for (int jj = 0; jj < 2; jj++)
                acc[ii][jj] = __builtin_amdgcn_mfma_f32_16x16x32_bf16(
                                  af[ii], bh[jj], acc[ii][jj], 0, 0, 0);
    }

    int col = lane & 15, rbase = (lane >> 4) * 4;
    #pragma unroll
    for (int ii = 0; ii < 2; ii++) {
        #pragma unroll
        for (int jj = 0; jj < 2; jj++) {
            #pragma unroll
            for (int rr = 0; rr < 4; rr++) {
                int gm = m0 + wm + ii * 16 + rbase + rr;
                int gn = n0 + wn + jj * 16 + col;
                float v = acc[ii][jj][rr];
                if (MODE == EPI_ROWBIAS)     v += bias[gm];
                else if (MODE == EPI_ROWDIV) v /= scale[gm];
                else                         v += bias[gn];
                size_t cix = (size_t)gm * ldc + gn;
                if (OUTF32) ((float*)C)[cix] = v;
                else        ((ushort_t*)C)[cix] = f2bf(v);
            }
        }
    }
}

// ---------------------------------------------------------------------------
// 1) prep: fused f32->bf16 convert (value/Wv/Wo) + MinHash signatures (full
//    u32 now -- exact vs reference) + zero the u8 match-count matrix M.
// ---------------------------------------------------------------------------
#define CVT_N0 (NB * LK * EDIM)
#define CVT_N1 (EDIM * EDIM)
#define CVT_N2 (EDIM * EDIM)
#define CVT_BLOCKS ((CVT_N0 + CVT_N1 + CVT_N2) / (256 * 8))   // 1280
#define MZ_BLOCKS 1024                                         // 4 MB / 4 KB
#define SIG_BLOCKS (NB * (LQ + LK) / 2)                        // 4096

__global__ __launch_bounds__(256) void prep_kernel(
        const float* __restrict__ v, const float* __restrict__ wv,
        const float* __restrict__ wo,
        ushort_t* __restrict__ vb, ushort_t* __restrict__ wvb,
        ushort_t* __restrict__ wob,
        const int* __restrict__ ts_q, const int* __restrict__ ts_k,
        const int* __restrict__ ha, const int* __restrict__ hb,
        unsigned* __restrict__ sig_q, unsigned* __restrict__ sig_k,
        uint8_t* __restrict__ Mz) {
    int blk = blockIdx.x;
    if (blk < CVT_BLOCKS) {               // ---- convert branch ----
        size_t i = ((size_t)blk * 256 + threadIdx.x) * 8;
        const float* src; ushort_t* dst; size_t off;
        if (i < CVT_N0)                { src = v;  dst = vb;  off = i; }
        else if (i < CVT_N0 + CVT_N1)  { src = wv; dst = wvb; off = i - CVT_N0; }
        else                           { src = wo; dst = wob; off = i - CVT_N0 - CVT_N1; }
        float4 a = *(const float4*)(src + off);
        float4 b = *(const float4*)(src + off + 4);
        ushort4 o0, o1;
        o0.x = f2bf(a.x); o0.y = f2bf(a.y); o0.z = f2bf(a.z); o0.w = f2bf(a.w);
        o1.x = f2bf(b.x); o1.y = f2bf(b.y); o1.z = f2bf(b.z); o1.w = f2bf(b.w);
        *(ushort4*)(dst + off)     = o0;
        *(ushort4*)(dst + off + 4) = o1;
        return;
    }
    if (blk < CVT_BLOCKS + MZ_BLOCKS) {   // ---- zero M branch (4 KB/block) ----
        size_t off = ((size_t)(blk - CVT_BLOCKS) * 256 + threadIdx.x) * 16;
        *(int4*)(Mz + off) = (int4){0, 0, 0, 0};
        return;
    }
    // ---- signature branch: 2 token-sets per block ----
    int sb = blk - CVT_BLOCKS - MZ_BLOCKS;   // 0..4095
    int half = threadIdx.x >> 7, k = threadIdx.x & 127;
    int row = sb * 2 + half;
    const int* ts = (row < NB * LQ) ? ts_q : ts_k;
    unsigned* sig = (row < NB * LQ) ? sig_q : sig_k;
    int idx = row & (NB * LQ - 1);
    unsigned long long a  = (unsigned)ha[k];
    unsigned long long bb = (unsigned)hb[k];
    __shared__ int ids[2][S_SET];
    if (k < S_SET) ids[half][k] = ts[idx * S_SET + k];
    __syncthreads();
    unsigned mn = 0xFFFFFFFFu;
    #pragma unroll
    for (int s = 0; s < S_SET; s++) {
        unsigned long long x = a * (unsigned long long)(unsigned)ids[half][s] + bb;
        x = (x & PRIME) + (x >> 31);      // 2^31 == 1 (mod 2^31-1)
        x = (x & PRIME) + (x >> 31);
        unsigned r = (unsigned)x;
        if (r >= PRIME) r -= PRIME;
        mn = (r < mn) ? r : mn;
    }
    sig[idx * K_HASH + k] = mn;
}

// ---------------------------------------------------------------------------
// 2) joing1: sparse equality-join replaces the dense 1024x1024x128 compare.
//    Match counts m(q,j) are nonzero for ~0.2% of pairs (random token sets
//    rarely share atoms; 31-bit minhash values almost never collide
//    otherwise), so per (b,k) we hash the 1024 sig_k column values into a
//    2048-slot LDS open-addressing table (duplicates inserted as separate
//    entries -> exact multiplicity) and probe with the 1024 sig_q values,
//    emitting byte atomicAdds into M[b][q][j]. O(L*K + matches) vs O(L^2*K):
//    ~1000x less work than the dense compare; exact for any data.
//    GEMM1 tiles stay fused: role = blk>>9 with CU = f(blk mod 256) (R12)
//    gives every CU 2 join + 2 GEMM blocks -> m114 MFMA/VALU co-schedule.
// ---------------------------------------------------------------------------
union JSmem {
    struct { unsigned keys[2048]; ushort_t vals[2048]; } j;   // 12 KB
    struct { ushort_t As[2][64 * 32]; ushort_t Bs[2][64 * 32]; } g; // 16 KB
};

__global__ __launch_bounds__(256) void joing1_kernel(
        const unsigned* __restrict__ sig_q, const unsigned* __restrict__ sig_k,
        uint8_t* __restrict__ M,
        const ushort_t* __restrict__ Wvb, const ushort_t* __restrict__ Vb,
        ushort_t* __restrict__ Vt, const float* __restrict__ bv) {
    __shared__ JSmem sm;
    int blk = blockIdx.x, tid = threadIdx.x;
    int t = blk & 511;
    if ((blk >> 9) == 0) {                // ---- GEMM1 tile ----
        gemm64_dev<0, EPI_ROWBIAS>(Wvb, Vb, Vt, bv, nullptr,
                                   EDIM, EDIM, NB * LK, EDIM,
                                   (t >> 6) * 64, (t & 63) * 64,
                                   sm.g.As[0], sm.g.Bs[0], tid);
        return;
    }
    // ---- join block: one (b, k) column pair ----
    int b = t >> 7, k = t & 127;
    for (int i = tid; i < 2048; i += 256) sm.j.keys[i] = 0xFFFFFFFFu;
    __syncthreads();
    const unsigned* skc = sig_k + (size_t)b * LK * K_HASH + k;
    const unsigned* sqc = sig_q + (size_t)b * LQ * K_HASH + k;
    // insert phase: all 1024 k-column values (dups kept as separate entries)
    for (int u = 0; u < 4; u++) {
        int j = u * 256 + tid;
        unsigned vv = skc[(size_t)j * K_HASH];
        unsigned h = (vv * 2654435761u) >> 21;       // top 11 bits -> [0,2048)
        while (true) {
            unsigned prev = atomicCAS(&sm.j.keys[h], 0xFFFFFFFFu, vv);
            if (prev == 0xFFFFFFFFu) { sm.j.vals[h] = (ushort_t)j; break; }
            h = (h + 1) & 2047;
        }
    }
    __syncthreads();
    // probe phase: each q value scans its cluster until EMPTY
    uint8_t* Mb = M + ((size_t)b << 20);
    for (int u = 0; u < 4; u++) {
        int q = u * 256 + tid;
        unsigned vv = sqc[(size_t)q * K_HASH];
        unsigned h = (vv * 2654435761u) >> 21;
        unsigned kk;
        while ((kk = sm.j.keys[h]) != 0xFFFFFFFFu) {
            if (kk == vv) {
                unsigned ix = ((unsigned)q << 10) + sm.j.vals[h];
                // byte-wise count: m <= 128 so no cross-byte carry
                atomicAdd((unsigned*)(Mb + (ix & ~3u)), 1u << ((ix & 3u) * 8));
            }
            h = (h + 1) & 2047;
        }
    }
}

// ---------------------------------------------------------------------------
// 3) lutrs: M (u8 counts) -> P (bf16 via score LUT) + exact row sums.
//    One block per q-row; rs written directly (no atomics).
// ---------------------------------------------------------------------------
__global__ __launch_bounds__(256) void lutrs_kernel(
        const uint8_t* __restrict__ M, ushort_t* __restrict__ P,
        float* __restrict__ rs) {
    __shared__ float lut[K_HASH + 1];
    __shared__ float wsum[4];
    int row = blockIdx.x, tid = threadIdx.x;
    if (tid <= K_HASH) {
        float r = (float)(K_HASH - tid) / (float)(K_HASH + tid); // (1-J)/(1+J)
        lut[tid] = expf(expf(-GAMMA * (2.0f * S_SET) * r));      // softmax numerator
    }
    __syncthreads();
    uchar4 m4 = *(const uchar4*)(M + (size_t)row * LK + tid * 4);
    float p0 = lut[m4.x], p1 = lut[m4.y], p2 = lut[m4.z], p3 = lut[m4.w];
    ushort4 o;
    o.x = f2bf(p0); o.y = f2bf(p1); o.z = f2bf(p2); o.w = f2bf(p3);
    *(ushort4*)(P + (size_t)row * LK + tid * 4) = o;
    float s = (p0 + p1) + (p2 + p3);
    #pragma unroll
    for (int off = 32; off; off >>= 1) s += __shfl_down(s, off);
    if ((tid & 63) == 0) wsum[tid >> 6] = s;
    __syncthreads();
    if (tid == 0) rs[row] = (wsum[0] + wsum[1]) + (wsum[2] + wsum[3]);
}

// ---------------------------------------------------------------------------
// 4/5) standalone BT-GEMM wrapper (z-batched) for GEMM2 / GEMM3
// ---------------------------------------------------------------------------
template<int OUTF32, int MODE>
__global__ __launch_bounds__(256) void btgemm_kernel(
        const ushort_t* __restrict__ A, const ushort_t* __restrict__ B,
        void* __restrict__ C,
        const float* __restrict__ bias, const float* __restrict__ scale,
        int lda, int ldb, int ldc, int Kd,
        long long sA, long long sB, long long sC, long long sS) {
    __shared__ ushort_t As[2][64 * 32], Bs[2][64 * 32];
    int z = blockIdx.z;
    gemm64_dev<OUTF32, MODE>(
        A + (size_t)z * sA, B + (size_t)z * sB,
        (char*)C + (size_t)z * sC * (OUTF32 ? 4 : 2),
        bias, scale + (size_t)z * sS,
        lda, ldb, ldc, Kd, blockIdx.y * 64, blockIdx.x * 64,
        As[0], Bs[0], threadIdx.x);
}

// ---------------------------------------------------------------------------
extern "C" void kernel_launch(void* const* d_in, const int* in_sizes, int n_in,
                              void* d_out, int out_size, void* d_ws, size_t ws_size,
                              hipStream_t stream) {
    // inputs: 0 query 1 key 2 value 3 ts_q 4 ts_k 5 ha 6 hb 7 Wq 8 bq 9 Wk 10 bk
    //         11 Wv 12 bv 13 Wo 14 bo   (q/k projections are dead code)
    const float* value = (const float*)d_in[2];
    const int* tsq = (const int*)d_in[3];
    const int* tsk = (const int*)d_in[4];
    const int* ha  = (const int*)d_in[5];
    const int* hb  = (const int*)d_in[6];
    const float* Wv = (const float*)d_in[11];
    const float* bv = (const float*)d_in[12];
    const float* Wo = (const float*)d_in[13];
    const float* bo = (const float*)d_in[14];
    float* out = (float*)d_out;

    char* ws = (char*)d_ws;
    unsigned* sigq = (unsigned*)(ws);                            // 2 MB (dead after joing1)
    unsigned* sigk = (unsigned*)(ws + (2ull << 20));             // 2 MB (dead after joing1)
    uint8_t*  M    = (uint8_t*)(ws + (4ull << 20));              // 4 MB (dead after lutrs)
    ushort_t* P    = (ushort_t*)(ws + (8ull << 20));             // 8 MB
    float*    rs   = (float*)(ws + (16ull << 20));               // 16 KB
    ushort_t* Vt   = (ushort_t*)(ws + (16ull << 20) + (64ull << 10)); // 4 MB [512 x 4096]
    ushort_t* ctx  = (ushort_t*)(ws);                            // 4 MB, aliases dead sigs
    ushort_t* Vb   = (ushort_t*)(ws + (20ull << 20) + (64ull << 10)); // 4 MB [4096 x 512]
    ushort_t* Wvb  = (ushort_t*)(ws + (24ull << 20) + (64ull << 10)); // 512 KB
    ushort_t* Wob  = (ushort_t*)(ws + (24ull << 20) + (64ull << 10) + (512ull << 10)); // 512 KB

    // 1) fused convert + signatures (u32) + zero M
    prep_kernel<<<CVT_BLOCKS + MZ_BLOCKS + SIG_BLOCKS, 256, 0, stream>>>(
        value, Wv, Wo, Vb, Wvb, Wob, tsq, tsk, ha, hb, sigq, sigk, M);

    // 2) sparse join || GEMM1, 2+2 blocks per CU
    joing1_kernel<<<1024, 256, 0, stream>>>(sigq, sigk, M, Wvb, Vb, Vt, bv);

    // 3) counts -> P (bf16) + row sums
    lutrs_kernel<<<NB * LQ, 256, 0, stream>>>(M, P, rs);

    // 4) ctx[b*1024+q, d] = (1/rs[b,q]) * sum_j P[b,q,j]*Vt[d, b*1024+j]
    btgemm_kernel<0, EPI_ROWDIV><<<dim3(EDIM / 64, LQ / 64, NB), 256, 0, stream>>>(
        P, Vt, ctx, bv /*unused*/, rs,
        LK, NB * LK, EDIM, LK,
        (long long)LQ * LK, (long long)LK, (long long)LQ * EDIM, (long long)LQ);

    // 5) out[bq, n] = sum_e ctx[bq,e]*Wob[n,e] + bo[n]  (f32 -> d_out)
    btgemm_kernel<1, EPI_COLBIAS><<<dim3(EDIM / 64, NB * LQ / 64, 1), 256, 0, stream>>>(
        ctx, Wob, out, bo, rs /*unused*/,
        EDIM, EDIM, EDIM, EDIM, 0LL, 0LL, 0LL, 0LL);
}